// Round 1
// baseline (313.407 us; speedup 1.0000x reference)
//
#include <hip/hip_runtime.h>
#include <hip/hip_bf16.h>

#define BATCH 16
#define SEQ   1024
#define DIM   1024

typedef __attribute__((ext_vector_type(8))) short bf16x8;
typedef __attribute__((ext_vector_type(4))) float f32x4;
typedef __attribute__((ext_vector_type(4))) unsigned short us4;

__device__ __forceinline__ float bfu2f(unsigned short u) {
  union { unsigned int i; float f; } c; c.i = ((unsigned int)u) << 16; return c.f;
}
__device__ __forceinline__ unsigned short f2bfu(float f) {
  union { float f; unsigned int i; } c; c.f = f;
  return (unsigned short)((c.i + 0x7FFFu + ((c.i >> 16) & 1u)) >> 16);
}
__device__ __forceinline__ void async16(void* lds, const void* g) {
  __builtin_amdgcn_global_load_lds(
      (const __attribute__((address_space(1))) unsigned int*)g,
      (__attribute__((address_space(3))) unsigned int*)lds, 16, 0, 0);
}

// ---------------- cast fp32 -> bf16 (vectorized) ----------------
__global__ void cast_f32_bf16(const float* __restrict__ in,
                              unsigned short* __restrict__ out, int n4) {
  int i = blockIdx.x * blockDim.x + threadIdx.x;
  if (i >= n4) return;
  f32x4 v = ((const f32x4*)in)[i];
  us4 o;
  o[0] = f2bfu(v[0]); o[1] = f2bfu(v[1]); o[2] = f2bfu(v[2]); o[3] = f2bfu(v[3]);
  ((us4*)out)[i] = o;
}

// ---------------- path-pool weights w[b,j] ----------------
// w[b,j] = (1/M_b) * sum_{i: pos[b,i]==1, s_i<=j<e_i} 1/(e_i-s_i)
__global__ void pathw_kernel(const int* __restrict__ pos, float* __restrict__ w) {
  const int b = blockIdx.x;
  __shared__ int ps[SEQ];
  __shared__ int mcnt;
  const int tid = threadIdx.x;
  if (tid == 0) mcnt = 0;
  __syncthreads();
  for (int i = tid; i < SEQ; i += 256) ps[i] = pos[b * SEQ + i];
  __syncthreads();
  int c = 0;
  for (int i = tid; i < SEQ; i += 256) c += ps[i];
  for (int o = 32; o; o >>= 1) c += __shfl_down(c, o);
  if ((tid & 63) == 0) atomicAdd(&mcnt, c);
  __syncthreads();
  const float invM = 1.0f / (float)mcnt;
  for (int j = tid; j < SEQ; j += 256) {
    float a = 0.f;
#pragma unroll
    for (int di = -1; di <= 1; ++di) {
      int i = j + di;
      if (i < 0 || i >= SEQ) continue;
      if (!ps[i]) continue;
      int s, e;
      if (i < 2) { s = 0; e = (i == 0) ? 2 : 3; }
      else { s = (ps[i - 2] == 1) ? i : (i - 1); e = i + 2; if (e > SEQ) e = SEQ; }
      if (s <= j && j < e) a += 1.0f / (float)(e - s);
    }
    w[b * SEQ + j] = a * invM;
  }
}

// ---------------- bf16 NT GEMM (m97 structure): C = bf16((A @ W^T + bias)*alpha)
__global__ void proj_gemm(const unsigned short* __restrict__ A,
                          const unsigned short* __restrict__ W,
                          const float* __restrict__ bias, float alpha,
                          unsigned short* __restrict__ C, int M, int N, int K)
{
  __shared__ __align__(16) unsigned short As[128 * 32];
  __shared__ __align__(16) unsigned short Bs[128 * 32];
  const int tid = threadIdx.x;
  const int wave = tid >> 6, lane = tid & 63;
  const int lr = lane & 15, lg = lane >> 4;
  const int wr = wave >> 1, wc = wave & 1;
  const int m0 = blockIdx.x * 128, n0 = blockIdx.y * 128;
  const int off0 = tid * 16, off1 = 4096 + tid * 16;
  const int r0 = off0 >> 6, ke0 = (off0 >> 1) & 31;
  const int r1 = off1 >> 6, ke1 = (off1 >> 1) & 31;
  f32x4 acc[4][4] = {};
  for (int kk = 0; kk < K; kk += 32) {
    async16((char*)As + off0, A + (size_t)(m0 + r0) * K + kk + ke0);
    async16((char*)As + off1, A + (size_t)(m0 + r1) * K + kk + ke1);
    async16((char*)Bs + off0, W + (size_t)(n0 + r0) * K + kk + ke0);
    async16((char*)Bs + off1, W + (size_t)(n0 + r1) * K + kk + ke1);
    __syncthreads();
    bf16x8 af[4], bfv[4];
#pragma unroll
    for (int i = 0; i < 4; ++i) {
      af[i]  = *(const bf16x8*)((const char*)As + ((wr * 64 + i * 16 + lr) << 6) + (lg << 4));
      bfv[i] = *(const bf16x8*)((const char*)Bs + ((wc * 64 + i * 16 + lr) << 6) + (lg << 4));
    }
#pragma unroll
    for (int i = 0; i < 4; ++i)
#pragma unroll
      for (int j = 0; j < 4; ++j)
        acc[i][j] = __builtin_amdgcn_mfma_f32_16x16x32_bf16(af[i], bfv[j], acc[i][j], 0, 0, 0);
    __syncthreads();
  }
#pragma unroll
  for (int j = 0; j < 4; ++j) {
    const int col = n0 + wc * 64 + j * 16 + lr;
    const float bc = bias[col];
#pragma unroll
    for (int i = 0; i < 4; ++i) {
      const int row = m0 + wr * 64 + i * 16 + lg * 4;
#pragma unroll
      for (int r = 0; r < 4; ++r)
        C[(size_t)(row + r) * N + col] = f2bfu((acc[i][j][r] + bc) * alpha);
    }
  }
}

// ---------------- per-batch E = exp(q@k^T + atom + var) ----------------
__global__ void qk_exp_kernel(const unsigned short* __restrict__ q,
                              const unsigned short* __restrict__ k,
                              const float* __restrict__ ag,
                              const float* __restrict__ vg,
                              unsigned short* __restrict__ E)
{
  __shared__ __align__(16) unsigned short As[128 * 32];
  __shared__ __align__(16) unsigned short Bs[128 * 32];
  const int b = blockIdx.z;
  const unsigned short* Aq = q + ((size_t)b << 20);
  const unsigned short* Bk = k + ((size_t)b << 20);
  const int tid = threadIdx.x;
  const int wave = tid >> 6, lane = tid & 63;
  const int lr = lane & 15, lg = lane >> 4;
  const int wr = wave >> 1, wc = wave & 1;
  const int m0 = blockIdx.y * 128, n0 = blockIdx.x * 128;
  const int off0 = tid * 16, off1 = 4096 + tid * 16;
  const int r0 = off0 >> 6, ke0 = (off0 >> 1) & 31;
  const int r1 = off1 >> 6, ke1 = (off1 >> 1) & 31;
  f32x4 acc[4][4] = {};
  for (int kk = 0; kk < DIM; kk += 32) {
    async16((char*)As + off0, Aq + (size_t)(m0 + r0) * DIM + kk + ke0);
    async16((char*)As + off1, Aq + (size_t)(m0 + r1) * DIM + kk + ke1);
    async16((char*)Bs + off0, Bk + (size_t)(n0 + r0) * DIM + kk + ke0);
    async16((char*)Bs + off1, Bk + (size_t)(n0 + r1) * DIM + kk + ke1);
    __syncthreads();
    bf16x8 af[4], bfv[4];
#pragma unroll
    for (int i = 0; i < 4; ++i) {
      af[i]  = *(const bf16x8*)((const char*)As + ((wr * 64 + i * 16 + lr) << 6) + (lg << 4));
      bfv[i] = *(const bf16x8*)((const char*)Bs + ((wc * 64 + i * 16 + lr) << 6) + (lg << 4));
    }
#pragma unroll
    for (int i = 0; i < 4; ++i)
#pragma unroll
      for (int j = 0; j < 4; ++j)
        acc[i][j] = __builtin_amdgcn_mfma_f32_16x16x32_bf16(af[i], bfv[j], acc[i][j], 0, 0, 0);
    __syncthreads();
  }
  const float* agb = ag + ((size_t)b << 20);
  const float* vgb = vg + ((size_t)b << 20);
  unsigned short* Eb = E + ((size_t)b << 20);
#pragma unroll
  for (int j = 0; j < 4; ++j) {
    const int col = n0 + wc * 64 + j * 16 + lr;
#pragma unroll
    for (int i = 0; i < 4; ++i) {
      const int row = m0 + wr * 64 + i * 16 + lg * 4;
#pragma unroll
      for (int r = 0; r < 4; ++r) {
        const size_t idx = (size_t)(row + r) * SEQ + col;
        const float l = acc[i][j][r] + agb[idx] + vgb[idx];
        Eb[idx] = f2bfu(__expf(l));
      }
    }
  }
}

// ---------------- row sums of E (softmax denominators) ----------------
__global__ void rowsum_kernel(const unsigned short* __restrict__ E,
                              float* __restrict__ denom) {
  const int row = blockIdx.x;  // b*SEQ + i
  const us4* p = (const us4*)(E + (size_t)row * SEQ);
  const int tid = threadIdx.x;
  us4 v = p[tid];
  float s = bfu2f(v[0]) + bfu2f(v[1]) + bfu2f(v[2]) + bfu2f(v[3]);
  for (int o = 32; o; o >>= 1) s += __shfl_down(s, o);
  __shared__ float red[4];
  if ((tid & 63) == 0) red[tid >> 6] = s;
  __syncthreads();
  if (tid == 0) denom[row] = red[0] + red[1] + red[2] + red[3];
}

// ---------------- weighted column sum: out[b,m] = sum_n c[b,n]*Mt[b,n,m]
// c = wv/dv (dv!=null) or wv. Partial over n-chunks of 128 for parallelism.
__global__ void wcolsum_part(const unsigned short* __restrict__ Mt,
                             const float* __restrict__ wv,
                             const float* __restrict__ dv,
                             float* __restrict__ part) {
  const int b = blockIdx.z;
  const int nc = blockIdx.y;  // 8 chunks of 128
  const int m = blockIdx.x * 256 + threadIdx.x;
  __shared__ float c[128];
  const int tid = threadIdx.x;
  if (tid < 128) {
    const int n = nc * 128 + tid;
    float cv = wv[b * SEQ + n];
    if (dv) cv /= dv[b * SEQ + n];
    c[tid] = cv;
  }
  __syncthreads();
  const unsigned short* p = Mt + ((size_t)b << 20) + ((size_t)(nc * 128) << 10) + m;
  float acc = 0.f;
#pragma unroll 8
  for (int n = 0; n < 128; ++n) acc += c[n] * bfu2f(p[(size_t)n << 10]);
  part[(size_t)((b * 8 + nc) << 10) + m] = acc;
}

__global__ void wcolsum_reduce(const float* __restrict__ part, float* __restrict__ out) {
  const int b = blockIdx.y;
  const int m = blockIdx.x * 256 + threadIdx.x;
  float s = 0.f;
#pragma unroll
  for (int nc = 0; nc < 8; ++nc) s += part[(size_t)((b * 8 + nc) << 10) + m];
  out[b * SEQ + m] = s;
}

// ---------------- item[b,h] = sum_d y[b,d]*Wv[h,d] + (sum_m u[b,m])*bv[h]
__global__ void item_kernel(const float* __restrict__ y, const float* __restrict__ u,
                            const unsigned short* __restrict__ Wvb,
                            const float* __restrict__ bv, float* __restrict__ item) {
  const int b = blockIdx.x;
  const int hblk = blockIdx.y;  // 256 blocks of 4 rows
  __shared__ float ys[DIM];
  __shared__ float sred[4];
  const int tid = threadIdx.x;
  float part = 0.f;
  for (int i = tid; i < DIM; i += 256) { ys[i] = y[b * DIM + i]; part += u[b * SEQ + i]; }
  for (int o = 32; o; o >>= 1) part += __shfl_down(part, o);
  if ((tid & 63) == 0) sred[tid >> 6] = part;
  __syncthreads();
  const float su = sred[0] + sred[1] + sred[2] + sred[3];
  const int wave = tid >> 6, lane = tid & 63;
  const int h = hblk * 4 + wave;
  const us4* wrow = (const us4*)(Wvb + (size_t)h * DIM);
  float acc = 0.f;
#pragma unroll
  for (int t = 0; t < 4; ++t) {
    us4 v = wrow[t * 64 + lane];
    const int d0 = (t * 64 + lane) * 4;
    acc += ys[d0] * bfu2f(v[0]) + ys[d0 + 1] * bfu2f(v[1]) +
           ys[d0 + 2] * bfu2f(v[2]) + ys[d0 + 3] * bfu2f(v[3]);
  }
  for (int o = 32; o; o >>= 1) acc += __shfl_down(acc, o);
  if (lane == 0) item[b * DIM + h] = acc + su * bv[h];
}

// ---------------- broadcast item[b,:] over n ----------------
__global__ void bcast_kernel(const float* __restrict__ item, float* __restrict__ out) {
  const int b = blockIdx.y;
  const int n = blockIdx.x;
  const f32x4* src = (const f32x4*)(item + b * DIM);
  f32x4* dst = (f32x4*)(out + (((size_t)b * SEQ + n) << 10));
  dst[threadIdx.x] = src[threadIdx.x];
}

extern "C" void kernel_launch(void* const* d_in, const int* in_sizes, int n_in,
                              void* d_out, int out_size, void* d_ws, size_t ws_size,
                              hipStream_t stream) {
  const float* x    = (const float*)d_in[0];
  const float* ag   = (const float*)d_in[1];
  const float* vgr  = (const float*)d_in[2];
  const float* Wq   = (const float*)d_in[3];
  const float* bq   = (const float*)d_in[4];
  const float* Wk   = (const float*)d_in[5];
  const float* bk   = (const float*)d_in[6];
  const float* Wv   = (const float*)d_in[7];
  const float* bv   = (const float*)d_in[8];
  const int*   pos  = (const int*)d_in[9];
  float* out = (float*)d_out;

  char* ws = (char*)d_ws;
  size_t off = 0;
  auto alloc = [&](size_t bytes) { void* p = ws + off; off += (bytes + 255) & ~(size_t)255; return p; };
  const size_t BNH = (size_t)BATCH * SEQ * DIM;           // 16.78M elems
  unsigned short* xb   = (unsigned short*)alloc(BNH * 2); // 33.5 MB
  unsigned short* qb   = (unsigned short*)alloc(BNH * 2);
  unsigned short* kb   = (unsigned short*)alloc(BNH * 2);
  unsigned short* E    = (unsigned short*)alloc(BNH * 2);
  unsigned short* Wqb  = (unsigned short*)alloc((size_t)DIM * DIM * 2);
  unsigned short* Wkb  = (unsigned short*)alloc((size_t)DIM * DIM * 2);
  unsigned short* Wvb  = (unsigned short*)alloc((size_t)DIM * DIM * 2);
  float* w     = (float*)alloc((size_t)BATCH * SEQ * 4);
  float* denom = (float*)alloc((size_t)BATCH * SEQ * 4);
  float* u     = (float*)alloc((size_t)BATCH * SEQ * 4);
  float* y     = (float*)alloc((size_t)BATCH * DIM * 4);
  float* item  = (float*)alloc((size_t)BATCH * DIM * 4);
  float* part  = (float*)alloc((size_t)BATCH * 8 * SEQ * 4);

  const float scale = 0.03125f;  // 1024^-0.5

  // casts
  cast_f32_bf16<<<(int)(BNH / 4 / 256), 256, 0, stream>>>(x, xb, (int)(BNH / 4));
  cast_f32_bf16<<<DIM * DIM / 4 / 256, 256, 0, stream>>>(Wq, Wqb, DIM * DIM / 4);
  cast_f32_bf16<<<DIM * DIM / 4 / 256, 256, 0, stream>>>(Wk, Wkb, DIM * DIM / 4);
  cast_f32_bf16<<<DIM * DIM / 4 / 256, 256, 0, stream>>>(Wv, Wvb, DIM * DIM / 4);

  // path-pool weights
  pathw_kernel<<<BATCH, 256, 0, stream>>>(pos, w);

  // q, k projections (q folds the 1/sqrt(H) scale)
  proj_gemm<<<dim3(128, 8), 256, 0, stream>>>(xb, Wqb, bq, scale, qb,
                                              BATCH * SEQ, DIM, DIM);
  proj_gemm<<<dim3(128, 8), 256, 0, stream>>>(xb, Wkb, bk, 1.0f, kb,
                                              BATCH * SEQ, DIM, DIM);

  // E = exp(logits)
  qk_exp_kernel<<<dim3(8, 8, BATCH), 256, 0, stream>>>(qb, kb, ag, vgr, E);

  // softmax denominators
  rowsum_kernel<<<BATCH * SEQ, 256, 0, stream>>>(E, denom);

  // u[b,m] = sum_n (w/denom)[b,n] * E[b,n,m]
  wcolsum_part<<<dim3(4, 8, BATCH), 256, 0, stream>>>(E, w, denom, part);
  wcolsum_reduce<<<dim3(4, BATCH), 256, 0, stream>>>(part, u);

  // y[b,d] = sum_m u[b,m] * x[b,m,d]
  wcolsum_part<<<dim3(4, 8, BATCH), 256, 0, stream>>>(xb, u, nullptr, part);
  wcolsum_reduce<<<dim3(4, BATCH), 256, 0, stream>>>(part, y);

  // item[b,h] = y@Wv^T + (sum u)*bv
  item_kernel<<<dim3(BATCH, 256), 256, 0, stream>>>(y, u, Wvb, bv, item);

  // broadcast to [B,N,H]
  bcast_kernel<<<dim3(SEQ, BATCH), 256, 0, stream>>>(item, out);
}

// Round 2
// 265.753 us; speedup vs baseline: 1.1793x; 1.1793x over previous
//
#include <hip/hip_runtime.h>
#include <hip/hip_bf16.h>

#define BATCH 16
#define SEQ   1024
#define DIM   1024

typedef __attribute__((ext_vector_type(8))) short bf16x8;
typedef __attribute__((ext_vector_type(4))) float f32x4;
typedef __attribute__((ext_vector_type(4))) unsigned short us4;

__device__ __forceinline__ float bfu2f(unsigned short u) {
  union { unsigned int i; float f; } c; c.i = ((unsigned int)u) << 16; return c.f;
}
__device__ __forceinline__ unsigned short f2bfu(float f) {
  union { float f; unsigned int i; } c; c.f = f;
  return (unsigned short)((c.i + 0x7FFFu + ((c.i >> 16) & 1u)) >> 16);
}
__device__ __forceinline__ void async16(void* lds, const void* g) {
  __builtin_amdgcn_global_load_lds(
      (const __attribute__((address_space(1))) unsigned int*)g,
      (__attribute__((address_space(3))) unsigned int*)lds, 16, 0, 0);
}

// ---------------- cast fp32 -> bf16 (vectorized) ----------------
__global__ void cast_f32_bf16(const float* __restrict__ in,
                              unsigned short* __restrict__ out, int n4) {
  int i = blockIdx.x * blockDim.x + threadIdx.x;
  if (i >= n4) return;
  f32x4 v = ((const f32x4*)in)[i];
  us4 o;
  o[0] = f2bfu(v[0]); o[1] = f2bfu(v[1]); o[2] = f2bfu(v[2]); o[3] = f2bfu(v[3]);
  ((us4*)out)[i] = o;
}

// ---------------- path-pool weights w[b,j]; also zero-inits denom ----------------
// w[b,j] = (1/M_b) * sum_{i: pos[b,i]==1, s_i<=j<e_i} 1/(e_i-s_i)
__global__ void pathw_kernel(const int* __restrict__ pos, float* __restrict__ w,
                             float* __restrict__ denom) {
  const int b = blockIdx.x;
  __shared__ int ps[SEQ];
  __shared__ int mcnt;
  const int tid = threadIdx.x;
  if (tid == 0) mcnt = 0;
  __syncthreads();
  for (int i = tid; i < SEQ; i += 256) {
    ps[i] = pos[b * SEQ + i];
    denom[b * SEQ + i] = 0.f;   // zero softmax denominators for qk_exp atomics
  }
  __syncthreads();
  int c = 0;
  for (int i = tid; i < SEQ; i += 256) c += ps[i];
  for (int o = 32; o; o >>= 1) c += __shfl_down(c, o);
  if ((tid & 63) == 0) atomicAdd(&mcnt, c);
  __syncthreads();
  const float invM = 1.0f / (float)mcnt;
  for (int j = tid; j < SEQ; j += 256) {
    float a = 0.f;
#pragma unroll
    for (int di = -1; di <= 1; ++di) {
      int i = j + di;
      if (i < 0 || i >= SEQ) continue;
      if (!ps[i]) continue;
      int s, e;
      if (i < 2) { s = 0; e = (i == 0) ? 2 : 3; }
      else { s = (ps[i - 2] == 1) ? i : (i - 1); e = i + 2; if (e > SEQ) e = SEQ; }
      if (s <= j && j < e) a += 1.0f / (float)(e - s);
    }
    w[b * SEQ + j] = a * invM;
  }
}

// ---------------- bf16 NT GEMM (m97 structure): C = bf16((A @ W^T + bias)*alpha)
__global__ void proj_gemm(const unsigned short* __restrict__ A,
                          const unsigned short* __restrict__ W,
                          const float* __restrict__ bias, float alpha,
                          unsigned short* __restrict__ C, int M, int N, int K)
{
  __shared__ __align__(16) unsigned short As[128 * 32];
  __shared__ __align__(16) unsigned short Bs[128 * 32];
  const int tid = threadIdx.x;
  const int wave = tid >> 6, lane = tid & 63;
  const int lr = lane & 15, lg = lane >> 4;
  const int wr = wave >> 1, wc = wave & 1;
  const int m0 = blockIdx.x * 128, n0 = blockIdx.y * 128;
  const int off0 = tid * 16, off1 = 4096 + tid * 16;
  const int r0 = off0 >> 6, ke0 = (off0 >> 1) & 31;
  const int r1 = off1 >> 6, ke1 = (off1 >> 1) & 31;
  f32x4 acc[4][4] = {};
  for (int kk = 0; kk < K; kk += 32) {
    async16((char*)As + off0, A + (size_t)(m0 + r0) * K + kk + ke0);
    async16((char*)As + off1, A + (size_t)(m0 + r1) * K + kk + ke1);
    async16((char*)Bs + off0, W + (size_t)(n0 + r0) * K + kk + ke0);
    async16((char*)Bs + off1, W + (size_t)(n0 + r1) * K + kk + ke1);
    __syncthreads();
    bf16x8 af[4], bfv[4];
#pragma unroll
    for (int i = 0; i < 4; ++i) {
      af[i]  = *(const bf16x8*)((const char*)As + ((wr * 64 + i * 16 + lr) << 6) + (lg << 4));
      bfv[i] = *(const bf16x8*)((const char*)Bs + ((wc * 64 + i * 16 + lr) << 6) + (lg << 4));
    }
#pragma unroll
    for (int i = 0; i < 4; ++i)
#pragma unroll
      for (int j = 0; j < 4; ++j)
        acc[i][j] = __builtin_amdgcn_mfma_f32_16x16x32_bf16(af[i], bfv[j], acc[i][j], 0, 0, 0);
    __syncthreads();
  }
#pragma unroll
  for (int j = 0; j < 4; ++j) {
    const int col = n0 + wc * 64 + j * 16 + lr;
    const float bc = bias[col];
#pragma unroll
    for (int i = 0; i < 4; ++i) {
      const int row = m0 + wr * 64 + i * 16 + lg * 4;
#pragma unroll
      for (int r = 0; r < 4; ++r)
        C[(size_t)(row + r) * N + col] = f2bfu((acc[i][j][r] + bc) * alpha);
    }
  }
}

// ---------------- per-batch E = exp(q@k^T + atom + var), fused rowsum ----------------
// Epilogue stages the fp32 acc tile through LDS so graph reads / E writes are
// fully coalesced (512B contiguous per 32-thread group); row-sum partials go to
// denom via one atomicAdd per 32-lane group.
__global__ void qk_exp_kernel(const unsigned short* __restrict__ q,
                              const unsigned short* __restrict__ k,
                              const float* __restrict__ ag,
                              const float* __restrict__ vg,
                              unsigned short* __restrict__ E,
                              float* __restrict__ denom)
{
  __shared__ __align__(16) unsigned short As[128 * 32];
  __shared__ __align__(16) unsigned short Bs[128 * 32];
  __shared__ __align__(16) float Sl[64 * 132];   // 64-row chunk, stride 132 (pad)
  const int b = blockIdx.z;
  const unsigned short* Aq = q + ((size_t)b << 20);
  const unsigned short* Bk = k + ((size_t)b << 20);
  const int tid = threadIdx.x;
  const int wave = tid >> 6, lane = tid & 63;
  const int lr = lane & 15, lg = lane >> 4;
  const int wr = wave >> 1, wc = wave & 1;
  const int m0 = blockIdx.y * 128, n0 = blockIdx.x * 128;
  const int off0 = tid * 16, off1 = 4096 + tid * 16;
  const int r0 = off0 >> 6, ke0 = (off0 >> 1) & 31;
  const int r1 = off1 >> 6, ke1 = (off1 >> 1) & 31;
  f32x4 acc[4][4] = {};
  for (int kk = 0; kk < DIM; kk += 32) {
    async16((char*)As + off0, Aq + (size_t)(m0 + r0) * DIM + kk + ke0);
    async16((char*)As + off1, Aq + (size_t)(m0 + r1) * DIM + kk + ke1);
    async16((char*)Bs + off0, Bk + (size_t)(n0 + r0) * DIM + kk + ke0);
    async16((char*)Bs + off1, Bk + (size_t)(n0 + r1) * DIM + kk + ke1);
    __syncthreads();
    bf16x8 af[4], bfv[4];
#pragma unroll
    for (int i = 0; i < 4; ++i) {
      af[i]  = *(const bf16x8*)((const char*)As + ((wr * 64 + i * 16 + lr) << 6) + (lg << 4));
      bfv[i] = *(const bf16x8*)((const char*)Bs + ((wc * 64 + i * 16 + lr) << 6) + (lg << 4));
    }
#pragma unroll
    for (int i = 0; i < 4; ++i)
#pragma unroll
      for (int j = 0; j < 4; ++j)
        acc[i][j] = __builtin_amdgcn_mfma_f32_16x16x32_bf16(af[i], bfv[j], acc[i][j], 0, 0, 0);
    __syncthreads();
  }
  const float* agb = ag + ((size_t)b << 20);
  const float* vgb = vg + ((size_t)b << 20);
  unsigned short* Eb = E + ((size_t)b << 20);
  float* dnb = denom + b * SEQ;
  // two 64-row phases: rows {p*32..p*32+31} U {64+p*32..64+p*32+31}
#pragma unroll
  for (int p = 0; p < 2; ++p) {
    __syncthreads();   // prior phase's Sl reads (or main loop) done
#pragma unroll
    for (int ii = 0; ii < 2; ++ii) {
      const int i = 2 * p + ii;
#pragma unroll
      for (int j = 0; j < 4; ++j)
#pragma unroll
        for (int r = 0; r < 4; ++r)
          Sl[(wr * 32 + ii * 16 + lg * 4 + r) * 132 + wc * 64 + j * 16 + lr] =
              acc[i][j][r];
    }
    __syncthreads();
#pragma unroll
    for (int it = 0; it < 8; ++it) {
      const int v = tid + it * 256;
      const int lrow = v >> 5, c4 = v & 31;
      const int grow = m0 + ((lrow < 32) ? (p * 32 + lrow) : (32 + p * 32 + lrow));
      const size_t base = (size_t)grow * SEQ + n0 + c4 * 4;
      const f32x4 a4 = *(const f32x4*)(agb + base);
      const f32x4 g4 = *(const f32x4*)(vgb + base);
      const f32x4 s4 = *(const f32x4*)(&Sl[lrow * 132 + c4 * 4]);
      const float e0 = __expf(s4[0] + a4[0] + g4[0]);
      const float e1 = __expf(s4[1] + a4[1] + g4[1]);
      const float e2 = __expf(s4[2] + a4[2] + g4[2]);
      const float e3 = __expf(s4[3] + a4[3] + g4[3]);
      us4 o;
      o[0] = f2bfu(e0); o[1] = f2bfu(e1); o[2] = f2bfu(e2); o[3] = f2bfu(e3);
      *(us4*)(Eb + base) = o;
      float rs = e0 + e1 + e2 + e3;
#pragma unroll
      for (int o2 = 16; o2; o2 >>= 1) rs += __shfl_down(rs, o2, 32);
      if ((tid & 31) == 0) atomicAdd(&dnb[grow], rs);
    }
  }
}

// ---------------- weighted column sum: out[b,m] = sum_n c[b,n]*Mt[b,n,m]
// c = wv/dv (dv!=null) or wv. Partial over n-chunks of 128 for parallelism.
__global__ void wcolsum_part(const unsigned short* __restrict__ Mt,
                             const float* __restrict__ wv,
                             const float* __restrict__ dv,
                             float* __restrict__ part) {
  const int b = blockIdx.z;
  const int nc = blockIdx.y;  // 8 chunks of 128
  const int m = blockIdx.x * 256 + threadIdx.x;
  __shared__ float c[128];
  const int tid = threadIdx.x;
  if (tid < 128) {
    const int n = nc * 128 + tid;
    float cv = wv[b * SEQ + n];
    if (dv) cv /= dv[b * SEQ + n];
    c[tid] = cv;
  }
  __syncthreads();
  const unsigned short* p = Mt + ((size_t)b << 20) + ((size_t)(nc * 128) << 10) + m;
  float acc = 0.f;
#pragma unroll 8
  for (int n = 0; n < 128; ++n) acc += c[n] * bfu2f(p[(size_t)n << 10]);
  part[(size_t)((b * 8 + nc) << 10) + m] = acc;
}

__global__ void wcolsum_reduce(const float* __restrict__ part, float* __restrict__ out) {
  const int b = blockIdx.y;
  const int m = blockIdx.x * 256 + threadIdx.x;
  float s = 0.f;
#pragma unroll
  for (int nc = 0; nc < 8; ++nc) s += part[(size_t)((b * 8 + nc) << 10) + m];
  out[b * SEQ + m] = s;
}

// ---------------- item[b,h] = sum_d y[b,d]*Wv[h,d] + (sum_m u[b,m])*bv[h]
__global__ void item_kernel(const float* __restrict__ y, const float* __restrict__ u,
                            const unsigned short* __restrict__ Wvb,
                            const float* __restrict__ bv, float* __restrict__ item) {
  const int b = blockIdx.x;
  const int hblk = blockIdx.y;  // 256 blocks of 4 rows
  __shared__ float ys[DIM];
  __shared__ float sred[4];
  const int tid = threadIdx.x;
  float part = 0.f;
  for (int i = tid; i < DIM; i += 256) { ys[i] = y[b * DIM + i]; part += u[b * SEQ + i]; }
  for (int o = 32; o; o >>= 1) part += __shfl_down(part, o);
  if ((tid & 63) == 0) sred[tid >> 6] = part;
  __syncthreads();
  const float su = sred[0] + sred[1] + sred[2] + sred[3];
  const int wave = tid >> 6, lane = tid & 63;
  const int h = hblk * 4 + wave;
  const us4* wrow = (const us4*)(Wvb + (size_t)h * DIM);
  float acc = 0.f;
#pragma unroll
  for (int t = 0; t < 4; ++t) {
    us4 v = wrow[t * 64 + lane];
    const int d0 = (t * 64 + lane) * 4;
    acc += ys[d0] * bfu2f(v[0]) + ys[d0 + 1] * bfu2f(v[1]) +
           ys[d0 + 2] * bfu2f(v[2]) + ys[d0 + 3] * bfu2f(v[3]);
  }
  for (int o = 32; o; o >>= 1) acc += __shfl_down(acc, o);
  if (lane == 0) item[b * DIM + h] = acc + su * bv[h];
}

// ---------------- broadcast item[b,:] over n ----------------
__global__ void bcast_kernel(const float* __restrict__ item, float* __restrict__ out) {
  const int b = blockIdx.y;
  const int n = blockIdx.x;
  const f32x4* src = (const f32x4*)(item + b * DIM);
  f32x4* dst = (f32x4*)(out + (((size_t)b * SEQ + n) << 10));
  dst[threadIdx.x] = src[threadIdx.x];
}

extern "C" void kernel_launch(void* const* d_in, const int* in_sizes, int n_in,
                              void* d_out, int out_size, void* d_ws, size_t ws_size,
                              hipStream_t stream) {
  const float* x    = (const float*)d_in[0];
  const float* ag   = (const float*)d_in[1];
  const float* vgr  = (const float*)d_in[2];
  const float* Wq   = (const float*)d_in[3];
  const float* bq   = (const float*)d_in[4];
  const float* Wk   = (const float*)d_in[5];
  const float* bk   = (const float*)d_in[6];
  const float* Wv   = (const float*)d_in[7];
  const float* bv   = (const float*)d_in[8];
  const int*   pos  = (const int*)d_in[9];
  float* out = (float*)d_out;

  char* ws = (char*)d_ws;
  size_t off = 0;
  auto alloc = [&](size_t bytes) { void* p = ws + off; off += (bytes + 255) & ~(size_t)255; return p; };
  const size_t BNH = (size_t)BATCH * SEQ * DIM;           // 16.78M elems
  unsigned short* xb   = (unsigned short*)alloc(BNH * 2); // 33.5 MB
  unsigned short* qb   = (unsigned short*)alloc(BNH * 2);
  unsigned short* kb   = (unsigned short*)alloc(BNH * 2);
  unsigned short* E    = (unsigned short*)alloc(BNH * 2);
  unsigned short* Wqb  = (unsigned short*)alloc((size_t)DIM * DIM * 2);
  unsigned short* Wkb  = (unsigned short*)alloc((size_t)DIM * DIM * 2);
  unsigned short* Wvb  = (unsigned short*)alloc((size_t)DIM * DIM * 2);
  float* w     = (float*)alloc((size_t)BATCH * SEQ * 4);
  float* denom = (float*)alloc((size_t)BATCH * SEQ * 4);
  float* u     = (float*)alloc((size_t)BATCH * SEQ * 4);
  float* y     = (float*)alloc((size_t)BATCH * DIM * 4);
  float* item  = (float*)alloc((size_t)BATCH * DIM * 4);
  float* part  = (float*)alloc((size_t)BATCH * 8 * SEQ * 4);

  const float scale = 0.03125f;  // 1024^-0.5

  // casts
  cast_f32_bf16<<<(int)(BNH / 4 / 256), 256, 0, stream>>>(x, xb, (int)(BNH / 4));
  cast_f32_bf16<<<DIM * DIM / 4 / 256, 256, 0, stream>>>(Wq, Wqb, DIM * DIM / 4);
  cast_f32_bf16<<<DIM * DIM / 4 / 256, 256, 0, stream>>>(Wk, Wkb, DIM * DIM / 4);
  cast_f32_bf16<<<DIM * DIM / 4 / 256, 256, 0, stream>>>(Wv, Wvb, DIM * DIM / 4);

  // path-pool weights (+ denom zero-init)
  pathw_kernel<<<BATCH, 256, 0, stream>>>(pos, w, denom);

  // q, k projections (q folds the 1/sqrt(H) scale)
  proj_gemm<<<dim3(128, 8), 256, 0, stream>>>(xb, Wqb, bq, scale, qb,
                                              BATCH * SEQ, DIM, DIM);
  proj_gemm<<<dim3(128, 8), 256, 0, stream>>>(xb, Wkb, bk, 1.0f, kb,
                                              BATCH * SEQ, DIM, DIM);

  // E = exp(logits), denom += rowsums (fused)
  qk_exp_kernel<<<dim3(8, 8, BATCH), 256, 0, stream>>>(qb, kb, ag, vgr, E, denom);

  // u[b,m] = sum_n (w/denom)[b,n] * E[b,n,m]
  wcolsum_part<<<dim3(4, 8, BATCH), 256, 0, stream>>>(E, w, denom, part);
  wcolsum_reduce<<<dim3(4, BATCH), 256, 0, stream>>>(part, u);

  // y[b,d] = sum_m u[b,m] * x[b,m,d]
  wcolsum_part<<<dim3(4, 8, BATCH), 256, 0, stream>>>(xb, u, nullptr, part);
  wcolsum_reduce<<<dim3(4, BATCH), 256, 0, stream>>>(part, y);

  // item[b,h] = y@Wv^T + (sum u)*bv
  item_kernel<<<dim3(BATCH, 256), 256, 0, stream>>>(y, u, Wvb, bv, item);

  // broadcast to [B,N,H]
  bcast_kernel<<<dim3(SEQ, BATCH), 256, 0, stream>>>(item, out);
}

// Round 3
// 242.686 us; speedup vs baseline: 1.2914x; 1.0950x over previous
//
#include <hip/hip_runtime.h>
#include <hip/hip_bf16.h>

#define BATCH 16
#define SEQ   1024
#define DIM   1024

typedef __attribute__((ext_vector_type(8))) short bf16x8;
typedef __attribute__((ext_vector_type(4))) float f32x4;
typedef __attribute__((ext_vector_type(4))) unsigned short us4;

__device__ __forceinline__ float bfu2f(unsigned short u) {
  union { unsigned int i; float f; } c; c.i = ((unsigned int)u) << 16; return c.f;
}
__device__ __forceinline__ unsigned short f2bfu(float f) {
  union { float f; unsigned int i; } c; c.f = f;
  return (unsigned short)((c.i + 0x7FFFu + ((c.i >> 16) & 1u)) >> 16);
}
__device__ __forceinline__ void async16(void* lds, const void* g) {
  __builtin_amdgcn_global_load_lds(
      (const __attribute__((address_space(1))) unsigned int*)g,
      (__attribute__((address_space(3))) unsigned int*)lds, 16, 0, 0);
}

// ---------------- cast fp32 -> bf16 (vectorized) ----------------
__global__ void cast_f32_bf16(const float* __restrict__ in,
                              unsigned short* __restrict__ out, int n4) {
  int i = blockIdx.x * blockDim.x + threadIdx.x;
  if (i >= n4) return;
  f32x4 v = ((const f32x4*)in)[i];
  us4 o;
  o[0] = f2bfu(v[0]); o[1] = f2bfu(v[1]); o[2] = f2bfu(v[2]); o[3] = f2bfu(v[3]);
  ((us4*)out)[i] = o;
}

// three weight casts in one dispatch (blockIdx.y selects the tensor)
__global__ void cast3_kernel(const float* __restrict__ a, const float* __restrict__ b,
                             const float* __restrict__ c,
                             unsigned short* __restrict__ oa,
                             unsigned short* __restrict__ ob,
                             unsigned short* __restrict__ oc) {
  const float* in; unsigned short* out;
  if (blockIdx.y == 0) { in = a; out = oa; }
  else if (blockIdx.y == 1) { in = b; out = ob; }
  else { in = c; out = oc; }
  const int i = blockIdx.x * 256 + threadIdx.x;
  f32x4 v = ((const f32x4*)in)[i];
  us4 o;
  o[0] = f2bfu(v[0]); o[1] = f2bfu(v[1]); o[2] = f2bfu(v[2]); o[3] = f2bfu(v[3]);
  ((us4*)out)[i] = o;
}

// ---------------- path-pool weights w[b,j]; also zero-inits denom ----------------
__global__ void pathw_kernel(const int* __restrict__ pos, float* __restrict__ w,
                             float* __restrict__ denom) {
  const int b = blockIdx.x;
  __shared__ int ps[SEQ];
  __shared__ int mcnt;
  const int tid = threadIdx.x;
  if (tid == 0) mcnt = 0;
  __syncthreads();
  for (int i = tid; i < SEQ; i += 256) {
    ps[i] = pos[b * SEQ + i];
    denom[b * SEQ + i] = 0.f;
  }
  __syncthreads();
  int c = 0;
  for (int i = tid; i < SEQ; i += 256) c += ps[i];
  for (int o = 32; o; o >>= 1) c += __shfl_down(c, o);
  if ((tid & 63) == 0) atomicAdd(&mcnt, c);
  __syncthreads();
  const float invM = 1.0f / (float)mcnt;
  for (int j = tid; j < SEQ; j += 256) {
    float a = 0.f;
#pragma unroll
    for (int di = -1; di <= 1; ++di) {
      int i = j + di;
      if (i < 0 || i >= SEQ) continue;
      if (!ps[i]) continue;
      int s, e;
      if (i < 2) { s = 0; e = (i == 0) ? 2 : 3; }
      else { s = (ps[i - 2] == 1) ? i : (i - 1); e = i + 2; if (e > SEQ) e = SEQ; }
      if (s <= j && j < e) a += 1.0f / (float)(e - s);
    }
    w[b * SEQ + j] = a * invM;
  }
}

// ---------------- bf16 NT GEMM: C = bf16((A @ W^T + bias)*alpha) ----------------
// Epilogue restages the fp32 acc tile through LDS (overlaid on As/Bs) in four
// 32-row phases; bias+alpha applied during the coalesced read-out.
__global__ void proj_gemm(const unsigned short* __restrict__ A,
                          const unsigned short* __restrict__ W,
                          const float* __restrict__ bias, float alpha,
                          unsigned short* __restrict__ C, int M, int N, int K)
{
  __shared__ __align__(16) char smem[16896];   // max(As+Bs=16384, Sl=32*132*4)
  unsigned short* As = (unsigned short*)smem;
  unsigned short* Bs = (unsigned short*)(smem + 8192);
  float* Sl = (float*)smem;
  const int tid = threadIdx.x;
  const int wave = tid >> 6, lane = tid & 63;
  const int lr = lane & 15, lg = lane >> 4;
  const int wr = wave >> 1, wc = wave & 1;
  const int m0 = blockIdx.x * 128, n0 = blockIdx.y * 128;
  const int off0 = tid * 16, off1 = 4096 + tid * 16;
  const int r0 = off0 >> 6, ke0 = (off0 >> 1) & 31;
  const int r1 = off1 >> 6, ke1 = (off1 >> 1) & 31;
  f32x4 acc[4][4] = {};
  for (int kk = 0; kk < K; kk += 32) {
    async16((char*)As + off0, A + (size_t)(m0 + r0) * K + kk + ke0);
    async16((char*)As + off1, A + (size_t)(m0 + r1) * K + kk + ke1);
    async16((char*)Bs + off0, W + (size_t)(n0 + r0) * K + kk + ke0);
    async16((char*)Bs + off1, W + (size_t)(n0 + r1) * K + kk + ke1);
    __syncthreads();
    bf16x8 af[4], bfv[4];
#pragma unroll
    for (int i = 0; i < 4; ++i) {
      af[i]  = *(const bf16x8*)((const char*)As + ((wr * 64 + i * 16 + lr) << 6) + (lg << 4));
      bfv[i] = *(const bf16x8*)((const char*)Bs + ((wc * 64 + i * 16 + lr) << 6) + (lg << 4));
    }
#pragma unroll
    for (int i = 0; i < 4; ++i)
#pragma unroll
      for (int j = 0; j < 4; ++j)
        acc[i][j] = __builtin_amdgcn_mfma_f32_16x16x32_bf16(af[i], bfv[j], acc[i][j], 0, 0, 0);
    __syncthreads();
  }
#pragma unroll
  for (int p = 0; p < 4; ++p) {
    __syncthreads();   // prior phase reads (or main-loop LDS use) done
    if (wr == (p >> 1)) {
      const int ibase = (p & 1) * 2;
#pragma unroll
      for (int ii = 0; ii < 2; ++ii) {
        const int i = ibase + ii;
#pragma unroll
        for (int j = 0; j < 4; ++j)
#pragma unroll
          for (int r = 0; r < 4; ++r)
            Sl[(ii * 16 + lg * 4 + r) * 132 + wc * 64 + j * 16 + lr] = acc[i][j][r];
      }
    }
    __syncthreads();
#pragma unroll
    for (int it = 0; it < 4; ++it) {
      const int v = tid + it * 256;          // 0..1023 = 32 rows x 32 f32x4
      const int lrow = v >> 5, c4 = v & 31;
      const int grow = m0 + p * 32 + lrow;
      const int col = n0 + c4 * 4;
      const f32x4 s4 = *(const f32x4*)(&Sl[lrow * 132 + c4 * 4]);
      const f32x4 b4 = *(const f32x4*)(bias + col);
      us4 o;
      o[0] = f2bfu((s4[0] + b4[0]) * alpha);
      o[1] = f2bfu((s4[1] + b4[1]) * alpha);
      o[2] = f2bfu((s4[2] + b4[2]) * alpha);
      o[3] = f2bfu((s4[3] + b4[3]) * alpha);
      *(us4*)(C + (size_t)grow * N + col) = o;
    }
  }
}

// ---------------- per-batch E = exp(q@k^T + atom + var), fused rowsum ----------------
// Sl overlaid on As/Bs, 32-row x 4 phases -> 16.9 KB LDS total.
__global__ void qk_exp_kernel(const unsigned short* __restrict__ q,
                              const unsigned short* __restrict__ k,
                              const float* __restrict__ ag,
                              const float* __restrict__ vg,
                              unsigned short* __restrict__ E,
                              float* __restrict__ denom)
{
  __shared__ __align__(16) char smem[16896];
  unsigned short* As = (unsigned short*)smem;
  unsigned short* Bs = (unsigned short*)(smem + 8192);
  float* Sl = (float*)smem;
  const int b = blockIdx.z;
  const unsigned short* Aq = q + ((size_t)b << 20);
  const unsigned short* Bk = k + ((size_t)b << 20);
  const int tid = threadIdx.x;
  const int wave = tid >> 6, lane = tid & 63;
  const int lr = lane & 15, lg = lane >> 4;
  const int wr = wave >> 1, wc = wave & 1;
  const int m0 = blockIdx.y * 128, n0 = blockIdx.x * 128;
  const int off0 = tid * 16, off1 = 4096 + tid * 16;
  const int r0 = off0 >> 6, ke0 = (off0 >> 1) & 31;
  const int r1 = off1 >> 6, ke1 = (off1 >> 1) & 31;
  f32x4 acc[4][4] = {};
  for (int kk = 0; kk < DIM; kk += 32) {
    async16((char*)As + off0, Aq + (size_t)(m0 + r0) * DIM + kk + ke0);
    async16((char*)As + off1, Aq + (size_t)(m0 + r1) * DIM + kk + ke1);
    async16((char*)Bs + off0, Bk + (size_t)(n0 + r0) * DIM + kk + ke0);
    async16((char*)Bs + off1, Bk + (size_t)(n0 + r1) * DIM + kk + ke1);
    __syncthreads();
    bf16x8 af[4], bfv[4];
#pragma unroll
    for (int i = 0; i < 4; ++i) {
      af[i]  = *(const bf16x8*)((const char*)As + ((wr * 64 + i * 16 + lr) << 6) + (lg << 4));
      bfv[i] = *(const bf16x8*)((const char*)Bs + ((wc * 64 + i * 16 + lr) << 6) + (lg << 4));
    }
#pragma unroll
    for (int i = 0; i < 4; ++i)
#pragma unroll
      for (int j = 0; j < 4; ++j)
        acc[i][j] = __builtin_amdgcn_mfma_f32_16x16x32_bf16(af[i], bfv[j], acc[i][j], 0, 0, 0);
    __syncthreads();
  }
  const float* agb = ag + ((size_t)b << 20);
  const float* vgb = vg + ((size_t)b << 20);
  unsigned short* Eb = E + ((size_t)b << 20);
  float* dnb = denom + b * SEQ;
#pragma unroll
  for (int p = 0; p < 4; ++p) {
    __syncthreads();
    if (wr == (p >> 1)) {
      const int ibase = (p & 1) * 2;
#pragma unroll
      for (int ii = 0; ii < 2; ++ii) {
        const int i = ibase + ii;
#pragma unroll
        for (int j = 0; j < 4; ++j)
#pragma unroll
          for (int r = 0; r < 4; ++r)
            Sl[(ii * 16 + lg * 4 + r) * 132 + wc * 64 + j * 16 + lr] = acc[i][j][r];
      }
    }
    __syncthreads();
#pragma unroll
    for (int it = 0; it < 4; ++it) {
      const int v = tid + it * 256;          // 32 rows x 32 f32x4
      const int lrow = v >> 5, c4 = v & 31;
      const int grow = m0 + p * 32 + lrow;
      const size_t base = (size_t)grow * SEQ + n0 + c4 * 4;
      const f32x4 a4 = *(const f32x4*)(agb + base);
      const f32x4 g4 = *(const f32x4*)(vgb + base);
      const f32x4 s4 = *(const f32x4*)(&Sl[lrow * 132 + c4 * 4]);
      const float e0 = __expf(s4[0] + a4[0] + g4[0]);
      const float e1 = __expf(s4[1] + a4[1] + g4[1]);
      const float e2 = __expf(s4[2] + a4[2] + g4[2]);
      const float e3 = __expf(s4[3] + a4[3] + g4[3]);
      us4 o;
      o[0] = f2bfu(e0); o[1] = f2bfu(e1); o[2] = f2bfu(e2); o[3] = f2bfu(e3);
      *(us4*)(Eb + base) = o;
      float rs = e0 + e1 + e2 + e3;
#pragma unroll
      for (int o2 = 16; o2; o2 >>= 1) rs += __shfl_down(rs, o2, 32);
      if ((tid & 31) == 0) atomicAdd(&dnb[grow], rs);
    }
  }
}

// ---------------- weighted column sum: out[b,m] = sum_n c[b,n]*Mt[b,n,m] ----------------
__global__ void wcolsum_part(const unsigned short* __restrict__ Mt,
                             const float* __restrict__ wv,
                             const float* __restrict__ dv,
                             float* __restrict__ part) {
  const int b = blockIdx.z;
  const int nc = blockIdx.y;
  const int m = blockIdx.x * 256 + threadIdx.x;
  __shared__ float c[128];
  const int tid = threadIdx.x;
  if (tid < 128) {
    const int n = nc * 128 + tid;
    float cv = wv[b * SEQ + n];
    if (dv) cv /= dv[b * SEQ + n];
    c[tid] = cv;
  }
  __syncthreads();
  const unsigned short* p = Mt + ((size_t)b << 20) + ((size_t)(nc * 128) << 10) + m;
  float acc = 0.f;
#pragma unroll 8
  for (int n = 0; n < 128; ++n) acc += c[n] * bfu2f(p[(size_t)n << 10]);
  part[(size_t)((b * 8 + nc) << 10) + m] = acc;
}

__global__ void wcolsum_reduce(const float* __restrict__ part, float* __restrict__ out) {
  const int b = blockIdx.y;
  const int m = blockIdx.x * 256 + threadIdx.x;
  float s = 0.f;
#pragma unroll
  for (int nc = 0; nc < 8; ++nc) s += part[(size_t)((b * 8 + nc) << 10) + m];
  out[b * SEQ + m] = s;
}

// ---------------- item[b,h] = sum_d y[b,d]*Wv[h,d] + (sum_m u[b,m])*bv[h] ----------------
__global__ void item_kernel(const float* __restrict__ y, const float* __restrict__ u,
                            const unsigned short* __restrict__ Wvb,
                            const float* __restrict__ bv, float* __restrict__ item) {
  const int b = blockIdx.x;
  const int hblk = blockIdx.y;
  __shared__ float ys[DIM];
  __shared__ float sred[4];
  const int tid = threadIdx.x;
  float part = 0.f;
  for (int i = tid; i < DIM; i += 256) { ys[i] = y[b * DIM + i]; part += u[b * SEQ + i]; }
  for (int o = 32; o; o >>= 1) part += __shfl_down(part, o);
  if ((tid & 63) == 0) sred[tid >> 6] = part;
  __syncthreads();
  const float su = sred[0] + sred[1] + sred[2] + sred[3];
  const int wave = tid >> 6, lane = tid & 63;
  const int h = hblk * 4 + wave;
  const us4* wrow = (const us4*)(Wvb + (size_t)h * DIM);
  float acc = 0.f;
#pragma unroll
  for (int t = 0; t < 4; ++t) {
    us4 v = wrow[t * 64 + lane];
    const int d0 = (t * 64 + lane) * 4;
    acc += ys[d0] * bfu2f(v[0]) + ys[d0 + 1] * bfu2f(v[1]) +
           ys[d0 + 2] * bfu2f(v[2]) + ys[d0 + 3] * bfu2f(v[3]);
  }
  for (int o = 32; o; o >>= 1) acc += __shfl_down(acc, o);
  if (lane == 0) item[b * DIM + h] = acc + su * bv[h];
}

// ---------------- broadcast item[b,:] over n ----------------
__global__ void bcast_kernel(const float* __restrict__ item, float* __restrict__ out) {
  const int b = blockIdx.y;
  const int n = blockIdx.x;
  const f32x4* src = (const f32x4*)(item + b * DIM);
  f32x4* dst = (f32x4*)(out + (((size_t)b * SEQ + n) << 10));
  dst[threadIdx.x] = src[threadIdx.x];
}

extern "C" void kernel_launch(void* const* d_in, const int* in_sizes, int n_in,
                              void* d_out, int out_size, void* d_ws, size_t ws_size,
                              hipStream_t stream) {
  const float* x    = (const float*)d_in[0];
  const float* ag   = (const float*)d_in[1];
  const float* vgr  = (const float*)d_in[2];
  const float* Wq   = (const float*)d_in[3];
  const float* bq   = (const float*)d_in[4];
  const float* Wk   = (const float*)d_in[5];
  const float* bk   = (const float*)d_in[6];
  const float* Wv   = (const float*)d_in[7];
  const float* bv   = (const float*)d_in[8];
  const int*   pos  = (const int*)d_in[9];
  float* out = (float*)d_out;

  char* ws = (char*)d_ws;
  size_t off = 0;
  auto alloc = [&](size_t bytes) { void* p = ws + off; off += (bytes + 255) & ~(size_t)255; return p; };
  const size_t BNH = (size_t)BATCH * SEQ * DIM;
  unsigned short* xb   = (unsigned short*)alloc(BNH * 2);
  unsigned short* qb   = (unsigned short*)alloc(BNH * 2);
  unsigned short* kb   = (unsigned short*)alloc(BNH * 2);
  unsigned short* E    = (unsigned short*)alloc(BNH * 2);
  unsigned short* Wqb  = (unsigned short*)alloc((size_t)DIM * DIM * 2);
  unsigned short* Wkb  = (unsigned short*)alloc((size_t)DIM * DIM * 2);
  unsigned short* Wvb  = (unsigned short*)alloc((size_t)DIM * DIM * 2);
  float* w     = (float*)alloc((size_t)BATCH * SEQ * 4);
  float* denom = (float*)alloc((size_t)BATCH * SEQ * 4);
  float* u     = (float*)alloc((size_t)BATCH * SEQ * 4);
  float* y     = (float*)alloc((size_t)BATCH * DIM * 4);
  float* item  = (float*)alloc((size_t)BATCH * DIM * 4);
  float* part  = (float*)alloc((size_t)BATCH * 8 * SEQ * 4);

  const float scale = 0.03125f;  // 1024^-0.5

  // casts
  cast_f32_bf16<<<(int)(BNH / 4 / 256), 256, 0, stream>>>(x, xb, (int)(BNH / 4));
  cast3_kernel<<<dim3(DIM * DIM / 4 / 256, 3), 256, 0, stream>>>(Wq, Wk, Wv, Wqb, Wkb, Wvb);

  // path-pool weights (+ denom zero-init)
  pathw_kernel<<<BATCH, 256, 0, stream>>>(pos, w, denom);

  // q, k projections (q folds the 1/sqrt(H) scale)
  proj_gemm<<<dim3(128, 8), 256, 0, stream>>>(xb, Wqb, bq, scale, qb,
                                              BATCH * SEQ, DIM, DIM);
  proj_gemm<<<dim3(128, 8), 256, 0, stream>>>(xb, Wkb, bk, 1.0f, kb,
                                              BATCH * SEQ, DIM, DIM);

  // E = exp(logits), denom += rowsums (fused)
  qk_exp_kernel<<<dim3(8, 8, BATCH), 256, 0, stream>>>(qb, kb, ag, vgr, E, denom);

  // u[b,m] = sum_n (w/denom)[b,n] * E[b,n,m]
  wcolsum_part<<<dim3(4, 8, BATCH), 256, 0, stream>>>(E, w, denom, part);
  wcolsum_reduce<<<dim3(4, BATCH), 256, 0, stream>>>(part, u);

  // y[b,d] = sum_m u[b,m] * x[b,m,d]
  wcolsum_part<<<dim3(4, 8, BATCH), 256, 0, stream>>>(xb, u, nullptr, part);
  wcolsum_reduce<<<dim3(4, BATCH), 256, 0, stream>>>(part, y);

  // item[b,h] = y@Wv^T + (sum u)*bv
  item_kernel<<<dim3(BATCH, 256), 256, 0, stream>>>(y, u, Wvb, bv, item);

  // broadcast to [B,N,H]
  bcast_kernel<<<dim3(SEQ, BATCH), 256, 0, stream>>>(item, out);
}

// Round 4
// 237.451 us; speedup vs baseline: 1.3199x; 1.0220x over previous
//
#include <hip/hip_runtime.h>
#include <hip/hip_bf16.h>

#define BATCH 16
#define SEQ   1024
#define DIM   1024

typedef __attribute__((ext_vector_type(8))) short bf16x8;
typedef __attribute__((ext_vector_type(4))) float f32x4;
typedef __attribute__((ext_vector_type(4))) unsigned short us4;

__device__ __forceinline__ float bfu2f(unsigned short u) {
  union { unsigned int i; float f; } c; c.i = ((unsigned int)u) << 16; return c.f;
}
__device__ __forceinline__ unsigned short f2bfu(float f) {
  union { float f; unsigned int i; } c; c.f = f;
  return (unsigned short)((c.i + 0x7FFFu + ((c.i >> 16) & 1u)) >> 16);
}
__device__ __forceinline__ void async16(void* lds, const void* g) {
  __builtin_amdgcn_global_load_lds(
      (const __attribute__((address_space(1))) unsigned int*)g,
      (__attribute__((address_space(3))) unsigned int*)lds, 16, 0, 0);
}

// ---------------- cast fp32 -> bf16 (vectorized) ----------------
__global__ void cast_f32_bf16(const float* __restrict__ in,
                              unsigned short* __restrict__ out, int n4) {
  int i = blockIdx.x * blockDim.x + threadIdx.x;
  if (i >= n4) return;
  f32x4 v = ((const f32x4*)in)[i];
  us4 o;
  o[0] = f2bfu(v[0]); o[1] = f2bfu(v[1]); o[2] = f2bfu(v[2]); o[3] = f2bfu(v[3]);
  ((us4*)out)[i] = o;
}

// ---------------- transpose-cast: out[i,h] = bf16(in[h,i]) for Wq, Wk ----------------
__global__ void castT_kernel(const float* __restrict__ Wq, const float* __restrict__ Wk,
                             unsigned short* __restrict__ WqT,
                             unsigned short* __restrict__ WkT) {
  const float* in = (blockIdx.z == 0) ? Wq : Wk;
  unsigned short* out = (blockIdx.z == 0) ? WqT : WkT;
  __shared__ float t[64][65];
  const int h0 = blockIdx.x * 64, i0 = blockIdx.y * 64;
  const int tid = threadIdx.x;
  const int sub = tid >> 4, c4 = tid & 15;
#pragma unroll
  for (int p = 0; p < 4; ++p) {
    const int row = p * 16 + sub;  // h-local
    f32x4 v = *(const f32x4*)(in + (size_t)(h0 + row) * DIM + i0 + c4 * 4);
    t[row][c4 * 4 + 0] = v[0]; t[row][c4 * 4 + 1] = v[1];
    t[row][c4 * 4 + 2] = v[2]; t[row][c4 * 4 + 3] = v[3];
  }
  __syncthreads();
#pragma unroll
  for (int p = 0; p < 4; ++p) {
    const int orow = p * 16 + sub;  // i-local
    us4 o;
    o[0] = f2bfu(t[c4 * 4 + 0][orow]);
    o[1] = f2bfu(t[c4 * 4 + 1][orow]);
    o[2] = f2bfu(t[c4 * 4 + 2][orow]);
    o[3] = f2bfu(t[c4 * 4 + 3][orow]);
    *(us4*)(out + (size_t)(i0 + orow) * DIM + h0 + c4 * 4) = o;
  }
}

// ---------------- t1 = WqT·bk, t2 = WkT·bq (row-dots) ----------------
__global__ void t12_kernel(const unsigned short* __restrict__ WqT,
                           const unsigned short* __restrict__ WkT,
                           const float* __restrict__ bq, const float* __restrict__ bk,
                           float* __restrict__ t1, float* __restrict__ t2) {
  const int y = blockIdx.y;
  const unsigned short* Wt = y ? WkT : WqT;
  const float* vec = y ? bq : bk;
  float* tout = y ? t2 : t1;
  const int wave = threadIdx.x >> 6, lane = threadIdx.x & 63;
  const int i = blockIdx.x * 4 + wave;
  const us4* wr = (const us4*)(Wt + (size_t)i * DIM);
  float s = 0.f;
#pragma unroll
  for (int t = 0; t < 4; ++t) {
    us4 w4 = wr[lane + 64 * t];
    f32x4 b4 = *(const f32x4*)(vec + (lane + 64 * t) * 4);
    s += bfu2f(w4[0]) * b4[0] + bfu2f(w4[1]) * b4[1] +
         bfu2f(w4[2]) * b4[2] + bfu2f(w4[3]) * b4[3];
  }
#pragma unroll
  for (int o = 32; o; o >>= 1) s += __shfl_down(s, o);
  if (lane == 0) tout[i] = s;
}

// ---------------- a[bn]=scale*(x_row·t1)+scale*(bq·bk); c[bn]=scale*(x_row·t2) ----------------
__global__ void ac_kernel(const unsigned short* __restrict__ xb,
                          const float* __restrict__ t1, const float* __restrict__ t2,
                          const float* __restrict__ bq, const float* __restrict__ bk,
                          float* __restrict__ a, float* __restrict__ c) {
  const float scale = 0.03125f;
  const int tid = threadIdx.x;
  const int wave = tid >> 6, lane = tid & 63;
  // d = bq·bk (block-wide)
  float dp = 0.f;
  for (int i = tid; i < DIM; i += 256) dp += bq[i] * bk[i];
#pragma unroll
  for (int o = 32; o; o >>= 1) dp += __shfl_down(dp, o);
  __shared__ float dred[4];
  if ((tid & 63) == 0) dred[tid >> 6] = dp;
  __syncthreads();
  const float d = dred[0] + dred[1] + dred[2] + dred[3];
  // per-lane chunks of t1/t2 matching the coalesced x layout
  float t1r[16], t2r[16];
#pragma unroll
  for (int t = 0; t < 4; ++t) {
    f32x4 v1 = *(const f32x4*)(t1 + (lane + 64 * t) * 4);
    f32x4 v2 = *(const f32x4*)(t2 + (lane + 64 * t) * 4);
#pragma unroll
    for (int j = 0; j < 4; ++j) { t1r[t * 4 + j] = v1[j]; t2r[t * 4 + j] = v2[j]; }
  }
  for (int rr = 0; rr < 16; ++rr) {
    const int row = blockIdx.x * 64 + wave * 16 + rr;
    const us4* xr = (const us4*)(xb + (size_t)row * DIM);
    float sa = 0.f, sc = 0.f;
#pragma unroll
    for (int t = 0; t < 4; ++t) {
      us4 v = xr[lane + 64 * t];
#pragma unroll
      for (int j = 0; j < 4; ++j) {
        const float f = bfu2f(v[j]);
        sa += f * t1r[t * 4 + j];
        sc += f * t2r[t * 4 + j];
      }
    }
#pragma unroll
    for (int o = 32; o; o >>= 1) { sa += __shfl_down(sa, o); sc += __shfl_down(sc, o); }
    if (lane == 0) {
      a[row] = scale * (sa + d);
      c[row] = scale * sc;
    }
  }
}

// ---------------- path-pool weights w[b,j]; zero-inits denom (+zbias via block 0) ----------------
__global__ void pathw_kernel(const int* __restrict__ pos, float* __restrict__ w,
                             float* __restrict__ denom, float* __restrict__ zbias) {
  const int b = blockIdx.x;
  __shared__ int ps[SEQ];
  __shared__ int mcnt;
  const int tid = threadIdx.x;
  if (tid == 0) mcnt = 0;
  __syncthreads();
  if (b == 0)
    for (int i = tid; i < DIM; i += 256) zbias[i] = 0.f;
  for (int i = tid; i < SEQ; i += 256) {
    ps[i] = pos[b * SEQ + i];
    denom[b * SEQ + i] = 0.f;
  }
  __syncthreads();
  int c = 0;
  for (int i = tid; i < SEQ; i += 256) c += ps[i];
  for (int o = 32; o; o >>= 1) c += __shfl_down(c, o);
  if ((tid & 63) == 0) atomicAdd(&mcnt, c);
  __syncthreads();
  const float invM = 1.0f / (float)mcnt;
  for (int j = tid; j < SEQ; j += 256) {
    float a = 0.f;
#pragma unroll
    for (int di = -1; di <= 1; ++di) {
      int i = j + di;
      if (i < 0 || i >= SEQ) continue;
      if (!ps[i]) continue;
      int s, e;
      if (i < 2) { s = 0; e = (i == 0) ? 2 : 3; }
      else { s = (ps[i - 2] == 1) ? i : (i - 1); e = i + 2; if (e > SEQ) e = SEQ; }
      if (s <= j && j < e) a += 1.0f / (float)(e - s);
    }
    w[b * SEQ + j] = a * invM;
  }
}

// ---------------- bf16 NT GEMM: C = bf16((A @ W^T + bias)*alpha) ----------------
__global__ void proj_gemm(const unsigned short* __restrict__ A,
                          const unsigned short* __restrict__ W,
                          const float* __restrict__ bias, float alpha,
                          unsigned short* __restrict__ C, int M, int N, int K)
{
  __shared__ __align__(16) char smem[16896];
  unsigned short* As = (unsigned short*)smem;
  unsigned short* Bs = (unsigned short*)(smem + 8192);
  float* Sl = (float*)smem;
  const int tid = threadIdx.x;
  const int wave = tid >> 6, lane = tid & 63;
  const int lr = lane & 15, lg = lane >> 4;
  const int wr = wave >> 1, wc = wave & 1;
  const int m0 = blockIdx.x * 128, n0 = blockIdx.y * 128;
  const int off0 = tid * 16, off1 = 4096 + tid * 16;
  const int r0 = off0 >> 6, ke0 = (off0 >> 1) & 31;
  const int r1 = off1 >> 6, ke1 = (off1 >> 1) & 31;
  f32x4 acc[4][4] = {};
  for (int kk = 0; kk < K; kk += 32) {
    async16((char*)As + off0, A + (size_t)(m0 + r0) * K + kk + ke0);
    async16((char*)As + off1, A + (size_t)(m0 + r1) * K + kk + ke1);
    async16((char*)Bs + off0, W + (size_t)(n0 + r0) * K + kk + ke0);
    async16((char*)Bs + off1, W + (size_t)(n0 + r1) * K + kk + ke1);
    __syncthreads();
    bf16x8 af[4], bfv[4];
#pragma unroll
    for (int i = 0; i < 4; ++i) {
      af[i]  = *(const bf16x8*)((const char*)As + ((wr * 64 + i * 16 + lr) << 6) + (lg << 4));
      bfv[i] = *(const bf16x8*)((const char*)Bs + ((wc * 64 + i * 16 + lr) << 6) + (lg << 4));
    }
#pragma unroll
    for (int i = 0; i < 4; ++i)
#pragma unroll
      for (int j = 0; j < 4; ++j)
        acc[i][j] = __builtin_amdgcn_mfma_f32_16x16x32_bf16(af[i], bfv[j], acc[i][j], 0, 0, 0);
    __syncthreads();
  }
#pragma unroll
  for (int p = 0; p < 4; ++p) {
    __syncthreads();
    if (wr == (p >> 1)) {
      const int ibase = (p & 1) * 2;
#pragma unroll
      for (int ii = 0; ii < 2; ++ii) {
        const int i = ibase + ii;
#pragma unroll
        for (int j = 0; j < 4; ++j)
#pragma unroll
          for (int r = 0; r < 4; ++r)
            Sl[(ii * 16 + lg * 4 + r) * 132 + wc * 64 + j * 16 + lr] = acc[i][j][r];
      }
    }
    __syncthreads();
#pragma unroll
    for (int it = 0; it < 4; ++it) {
      const int v = tid + it * 256;
      const int lrow = v >> 5, c4 = v & 31;
      const int grow = m0 + p * 32 + lrow;
      const int col = n0 + c4 * 4;
      const f32x4 s4 = *(const f32x4*)(&Sl[lrow * 132 + c4 * 4]);
      const f32x4 b4 = *(const f32x4*)(bias + col);
      us4 o;
      o[0] = f2bfu((s4[0] + b4[0]) * alpha);
      o[1] = f2bfu((s4[1] + b4[1]) * alpha);
      o[2] = f2bfu((s4[2] + b4[2]) * alpha);
      o[3] = f2bfu((s4[3] + b4[3]) * alpha);
      *(us4*)(C + (size_t)grow * N + col) = o;
    }
  }
}

// ---------------- per-batch E = exp(z@x^T + a_n + c_m + atom + var), fused rowsum ----------------
__global__ void qk_exp_kernel(const unsigned short* __restrict__ z,
                              const unsigned short* __restrict__ xb,
                              const float* __restrict__ ag,
                              const float* __restrict__ vg,
                              const float* __restrict__ av,
                              const float* __restrict__ cv,
                              unsigned short* __restrict__ E,
                              float* __restrict__ denom)
{
  __shared__ __align__(16) char smem[16896];
  unsigned short* As = (unsigned short*)smem;
  unsigned short* Bs = (unsigned short*)(smem + 8192);
  float* Sl = (float*)smem;
  const int b = blockIdx.z;
  const unsigned short* Aq = z + ((size_t)b << 20);
  const unsigned short* Bk = xb + ((size_t)b << 20);
  const int tid = threadIdx.x;
  const int wave = tid >> 6, lane = tid & 63;
  const int lr = lane & 15, lg = lane >> 4;
  const int wr = wave >> 1, wc = wave & 1;
  const int m0 = blockIdx.y * 128, n0 = blockIdx.x * 128;
  const int off0 = tid * 16, off1 = 4096 + tid * 16;
  const int r0 = off0 >> 6, ke0 = (off0 >> 1) & 31;
  const int r1 = off1 >> 6, ke1 = (off1 >> 1) & 31;
  f32x4 acc[4][4] = {};
  for (int kk = 0; kk < DIM; kk += 32) {
    async16((char*)As + off0, Aq + (size_t)(m0 + r0) * DIM + kk + ke0);
    async16((char*)As + off1, Aq + (size_t)(m0 + r1) * DIM + kk + ke1);
    async16((char*)Bs + off0, Bk + (size_t)(n0 + r0) * DIM + kk + ke0);
    async16((char*)Bs + off1, Bk + (size_t)(n0 + r1) * DIM + kk + ke1);
    __syncthreads();
    bf16x8 af[4], bfv[4];
#pragma unroll
    for (int i = 0; i < 4; ++i) {
      af[i]  = *(const bf16x8*)((const char*)As + ((wr * 64 + i * 16 + lr) << 6) + (lg << 4));
      bfv[i] = *(const bf16x8*)((const char*)Bs + ((wc * 64 + i * 16 + lr) << 6) + (lg << 4));
    }
#pragma unroll
    for (int i = 0; i < 4; ++i)
#pragma unroll
      for (int j = 0; j < 4; ++j)
        acc[i][j] = __builtin_amdgcn_mfma_f32_16x16x32_bf16(af[i], bfv[j], acc[i][j], 0, 0, 0);
    __syncthreads();
  }
  const float* agb = ag + ((size_t)b << 20);
  const float* vgb = vg + ((size_t)b << 20);
  unsigned short* Eb = E + ((size_t)b << 20);
  float* dnb = denom + b * SEQ;
  const float* avb = av + b * SEQ;
  const float* cvb = cv + b * SEQ;
#pragma unroll
  for (int p = 0; p < 4; ++p) {
    __syncthreads();
    if (wr == (p >> 1)) {
      const int ibase = (p & 1) * 2;
#pragma unroll
      for (int ii = 0; ii < 2; ++ii) {
        const int i = ibase + ii;
#pragma unroll
        for (int j = 0; j < 4; ++j)
#pragma unroll
          for (int r = 0; r < 4; ++r)
            Sl[(ii * 16 + lg * 4 + r) * 132 + wc * 64 + j * 16 + lr] = acc[i][j][r];
      }
    }
    __syncthreads();
#pragma unroll
    for (int it = 0; it < 4; ++it) {
      const int v = tid + it * 256;
      const int lrow = v >> 5, c4 = v & 31;
      const int grow = m0 + p * 32 + lrow;
      const size_t base = (size_t)grow * SEQ + n0 + c4 * 4;
      const f32x4 a4 = *(const f32x4*)(agb + base);
      const f32x4 g4 = *(const f32x4*)(vgb + base);
      const f32x4 c4v = *(const f32x4*)(cvb + n0 + c4 * 4);
      const float arow = avb[grow];
      const f32x4 s4 = *(const f32x4*)(&Sl[lrow * 132 + c4 * 4]);
      const float e0 = __expf(s4[0] + a4[0] + g4[0] + arow + c4v[0]);
      const float e1 = __expf(s4[1] + a4[1] + g4[1] + arow + c4v[1]);
      const float e2 = __expf(s4[2] + a4[2] + g4[2] + arow + c4v[2]);
      const float e3 = __expf(s4[3] + a4[3] + g4[3] + arow + c4v[3]);
      us4 o;
      o[0] = f2bfu(e0); o[1] = f2bfu(e1); o[2] = f2bfu(e2); o[3] = f2bfu(e3);
      *(us4*)(Eb + base) = o;
      float rs = e0 + e1 + e2 + e3;
#pragma unroll
      for (int o2 = 16; o2; o2 >>= 1) rs += __shfl_down(rs, o2, 32);
      if ((tid & 31) == 0) atomicAdd(&dnb[grow], rs);
    }
  }
}

// ---------------- weighted column sum ----------------
__global__ void wcolsum_part(const unsigned short* __restrict__ Mt,
                             const float* __restrict__ wv,
                             const float* __restrict__ dv,
                             float* __restrict__ part) {
  const int b = blockIdx.z;
  const int nc = blockIdx.y;
  const int m = blockIdx.x * 256 + threadIdx.x;
  __shared__ float c[128];
  const int tid = threadIdx.x;
  if (tid < 128) {
    const int n = nc * 128 + tid;
    float cvw = wv[b * SEQ + n];
    if (dv) cvw /= dv[b * SEQ + n];
    c[tid] = cvw;
  }
  __syncthreads();
  const unsigned short* p = Mt + ((size_t)b << 20) + ((size_t)(nc * 128) << 10) + m;
  float acc = 0.f;
#pragma unroll 8
  for (int n = 0; n < 128; ++n) acc += c[n] * bfu2f(p[(size_t)n << 10]);
  part[(size_t)((b * 8 + nc) << 10) + m] = acc;
}

__global__ void wcolsum_reduce(const float* __restrict__ part, float* __restrict__ out) {
  const int b = blockIdx.y;
  const int m = blockIdx.x * 256 + threadIdx.x;
  float s = 0.f;
#pragma unroll
  for (int nc = 0; nc < 8; ++nc) s += part[(size_t)((b * 8 + nc) << 10) + m];
  out[b * SEQ + m] = s;
}

// ---------------- item[b,h] = sum_d y[b,d]*Wv[h,d] + (sum_m u[b,m])*bv[h] ----------------
__global__ void item_kernel(const float* __restrict__ y, const float* __restrict__ u,
                            const unsigned short* __restrict__ Wvb,
                            const float* __restrict__ bv, float* __restrict__ item) {
  const int b = blockIdx.x;
  const int hblk = blockIdx.y;
  __shared__ float ys[DIM];
  __shared__ float sred[4];
  const int tid = threadIdx.x;
  float part = 0.f;
  for (int i = tid; i < DIM; i += 256) { ys[i] = y[b * DIM + i]; part += u[b * SEQ + i]; }
  for (int o = 32; o; o >>= 1) part += __shfl_down(part, o);
  if ((tid & 63) == 0) sred[tid >> 6] = part;
  __syncthreads();
  const float su = sred[0] + sred[1] + sred[2] + sred[3];
  const int wave = tid >> 6, lane = tid & 63;
  const int h = hblk * 4 + wave;
  const us4* wrow = (const us4*)(Wvb + (size_t)h * DIM);
  float acc = 0.f;
#pragma unroll
  for (int t = 0; t < 4; ++t) {
    us4 v = wrow[t * 64 + lane];
    const int d0 = (t * 64 + lane) * 4;
    acc += ys[d0] * bfu2f(v[0]) + ys[d0 + 1] * bfu2f(v[1]) +
           ys[d0 + 2] * bfu2f(v[2]) + ys[d0 + 3] * bfu2f(v[3]);
  }
  for (int o = 32; o; o >>= 1) acc += __shfl_down(acc, o);
  if (lane == 0) item[b * DIM + h] = acc + su * bv[h];
}

// ---------------- broadcast item[b,:] over n ----------------
__global__ void bcast_kernel(const float* __restrict__ item, float* __restrict__ out) {
  const int b = blockIdx.y;
  const int n = blockIdx.x;
  const f32x4* src = (const f32x4*)(item + b * DIM);
  f32x4* dst = (f32x4*)(out + (((size_t)b * SEQ + n) << 10));
  dst[threadIdx.x] = src[threadIdx.x];
}

extern "C" void kernel_launch(void* const* d_in, const int* in_sizes, int n_in,
                              void* d_out, int out_size, void* d_ws, size_t ws_size,
                              hipStream_t stream) {
  const float* x    = (const float*)d_in[0];
  const float* ag   = (const float*)d_in[1];
  const float* vgr  = (const float*)d_in[2];
  const float* Wq   = (const float*)d_in[3];
  const float* bq   = (const float*)d_in[4];
  const float* Wk   = (const float*)d_in[5];
  const float* bk   = (const float*)d_in[6];
  const float* Wv   = (const float*)d_in[7];
  const float* bv   = (const float*)d_in[8];
  const int*   pos  = (const int*)d_in[9];
  float* out = (float*)d_out;

  char* ws = (char*)d_ws;
  size_t off = 0;
  auto alloc = [&](size_t bytes) { void* p = ws + off; off += (bytes + 255) & ~(size_t)255; return p; };
  const size_t BNH = (size_t)BATCH * SEQ * DIM;
  unsigned short* xb   = (unsigned short*)alloc(BNH * 2);
  unsigned short* zb   = (unsigned short*)alloc(BNH * 2);
  unsigned short* E    = (unsigned short*)alloc(BNH * 2);
  unsigned short* WqT  = (unsigned short*)alloc((size_t)DIM * DIM * 2);
  unsigned short* WkT  = (unsigned short*)alloc((size_t)DIM * DIM * 2);
  unsigned short* Wvb  = (unsigned short*)alloc((size_t)DIM * DIM * 2);
  unsigned short* Hb   = (unsigned short*)alloc((size_t)DIM * DIM * 2);
  float* w     = (float*)alloc((size_t)BATCH * SEQ * 4);
  float* denom = (float*)alloc((size_t)BATCH * SEQ * 4);
  float* u     = (float*)alloc((size_t)BATCH * SEQ * 4);
  float* av    = (float*)alloc((size_t)BATCH * SEQ * 4);
  float* cvv   = (float*)alloc((size_t)BATCH * SEQ * 4);
  float* t1    = (float*)alloc((size_t)DIM * 4);
  float* t2    = (float*)alloc((size_t)DIM * 4);
  float* zbias = (float*)alloc((size_t)DIM * 4);
  float* y     = (float*)alloc((size_t)BATCH * DIM * 4);
  float* item  = (float*)alloc((size_t)BATCH * DIM * 4);
  float* part  = (float*)alloc((size_t)BATCH * 8 * SEQ * 4);

  const float scale = 0.03125f;  // 1024^-0.5

  // casts: x -> xb, Wv -> Wvb, Wq/Wk -> transposed bf16
  cast_f32_bf16<<<(int)(BNH / 4 / 256), 256, 0, stream>>>(x, xb, (int)(BNH / 4));
  cast_f32_bf16<<<DIM * DIM / 4 / 256, 256, 0, stream>>>(Wv, Wvb, DIM * DIM / 4);
  castT_kernel<<<dim3(16, 16, 2), 256, 0, stream>>>(Wq, Wk, WqT, WkT);

  // path-pool weights (+ denom/zbias zero-init)
  pathw_kernel<<<BATCH, 256, 0, stream>>>(pos, w, denom, zbias);

  // bias-fold vectors
  t12_kernel<<<dim3(256, 2), 256, 0, stream>>>(WqT, WkT, bq, bk, t1, t2);
  ac_kernel<<<256, 256, 0, stream>>>(xb, t1, t2, bq, bk, av, cvv);

  // H = scale * (Wk^T Wq)  [H[i,j] = scale*sum_t Wk[t,i]Wq[t,j]]
  proj_gemm<<<dim3(8, 8), 256, 0, stream>>>(WkT, WqT, zbias, scale, Hb, DIM, DIM, DIM);

  // z = x @ H^T  (z[n,i] = scale*(x G)[n,i])
  proj_gemm<<<dim3(128, 8), 256, 0, stream>>>(xb, Hb, zbias, 1.0f, zb,
                                              BATCH * SEQ, DIM, DIM);

  // E = exp(z x^T + a + c + graphs), denom += rowsums
  qk_exp_kernel<<<dim3(8, 8, BATCH), 256, 0, stream>>>(zb, xb, ag, vgr, av, cvv, E, denom);

  // u[b,m] = sum_n (w/denom)[b,n] * E[b,n,m]
  wcolsum_part<<<dim3(4, 8, BATCH), 256, 0, stream>>>(E, w, denom, part);
  wcolsum_reduce<<<dim3(4, BATCH), 256, 0, stream>>>(part, u);

  // y[b,d] = sum_m u[b,m] * x[b,m,d]
  wcolsum_part<<<dim3(4, 8, BATCH), 256, 0, stream>>>(xb, u, nullptr, part);
  wcolsum_reduce<<<dim3(4, BATCH), 256, 0, stream>>>(part, y);

  // item[b,h] = y@Wv^T + (sum u)*bv
  item_kernel<<<dim3(BATCH, 256), 256, 0, stream>>>(y, u, Wvb, bv, item);

  // broadcast to [B,N,H]
  bcast_kernel<<<dim3(SEQ, BATCH), 256, 0, stream>>>(item, out);
}